// Round 7
// baseline (136.009 us; speedup 1.0000x reference)
//
#include <hip/hip_runtime.h>
#include <hip/hip_bf16.h>
#include <cstdint>

// DenseMRConv: out = concat([x, max_k(x[idx[n,k]] - x[n])]) @ W + b
// N=100000, K=32, d=64, d_out=64.
//
// R7: break the gather serialization. (a) no LDS index staging — lane-half h
// owns contiguous neighbors [16h,16h+16), indices loaded as 4x int4 straight
// from ei (8-way broadcast across e-lanes is free) -> no lgkm dependency in
// the gather loop, one less __syncthreads. (b) launch_bounds(256,4) (VGPR cap
// 128) + flat r[16] batch + pairwise max tree so the scheduler keeps ~16
// gathers in flight (R6's VGPR=32 proved it was pipelining to ~2).
// (c) per-node x / xbfB row loads issued before the gather loop.

typedef __attribute__((ext_vector_type(8))) short short8;
typedef __attribute__((ext_vector_type(4))) float f4;

#define TILE 16
#define ROWS 168   // padded h row stride in bf16 elems (336 B, 16B-aligned)
#define BIAS 8.0f

__device__ __forceinline__ unsigned short f2bf(float f) {
  unsigned int u = __builtin_bit_cast(unsigned int, f);
  u += 0x7fffu + ((u >> 16) & 1u);          // round-to-nearest-even
  return (unsigned short)(u >> 16);
}
__device__ __forceinline__ unsigned int pack2(float a, float b) {
  return (unsigned int)f2bf(a) | ((unsigned int)f2bf(b) << 16);
}
__device__ __forceinline__ float bflo(unsigned int u) {
  return __builtin_bit_cast(float, u << 16);
}
__device__ __forceinline__ float bfhi(unsigned int u) {
  return __builtin_bit_cast(float, u & 0xffff0000u);
}
__device__ __forceinline__ unsigned int pkmax(unsigned int a, unsigned int b) {
  unsigned int d;
  asm("v_pk_max_u16 %0, %1, %2" : "=v"(d) : "v"(a), "v"(b));
  return d;
}
__device__ __forceinline__ uint4 pkmax4(uint4 a, uint4 b) {
  uint4 d;
  d.x = pkmax(a.x, b.x); d.y = pkmax(a.y, b.y);
  d.z = pkmax(a.z, b.z); d.w = pkmax(a.w, b.w);
  return d;
}

// ---- pass 1: x -> biased bf16 copy (blocks [0,nxb)), W -> B-frags (block nxb)
__global__ __launch_bounds__(256)
void convert_kernel(const float* __restrict__ x, unsigned int* __restrict__ xbfB,
                    const float* __restrict__ W, unsigned short* __restrict__ wf,
                    int n8, int nxb) {
  if ((int)blockIdx.x < nxb) {
    int i = blockIdx.x * 256 + threadIdx.x;
    if (i >= n8) return;
    const f4* p = (const f4*)x + (size_t)i * 2;
    f4 a = p[0], b = p[1];
    uint4 w;
    w.x = pack2(a.x + BIAS, a.y + BIAS); w.y = pack2(a.z + BIAS, a.w + BIAS);
    w.z = pack2(b.x + BIAS, b.y + BIAS); w.w = pack2(b.z + BIAS, b.w + BIAS);
    ((uint4*)xbfB)[i] = w;
  } else {
    // B layout for mfma_f32_16x16x32_bf16: lane holds B[k=(l>>4)*8+j][n=l&15].
    #pragma unroll
    for (int q = 0; q < 4; ++q) {
      int idx = threadIdx.x * 4 + q;
      int wv = idx >> 8, ks = (idx >> 6) & 3, l = idx & 63;
      int c = l & 15, g = l >> 4;
      short8 v;
      #pragma unroll
      for (int j = 0; j < 8; ++j)
        v[j] = (short)f2bf(W[(ks * 32 + g * 8 + j) * 64 + wv * 16 + c]);
      *(short8*)(wf + (size_t)idx * 8) = v;
    }
  }
}

// ---- pass 2: gather + packed-max + MFMA GEMM. One block per 16-node tile.
__global__ __launch_bounds__(256, 4)
void mrconv5_kernel(const float* __restrict__ x,
                    const unsigned int* __restrict__ xbfB,  // bf16(x+8), 2/uint
                    const unsigned short* __restrict__ wf,  // prebuilt B-frags
                    const int* __restrict__ ei,
                    const float* __restrict__ bias,
                    float* __restrict__ out,
                    int n_tiles)
{
  __shared__ __align__(16) unsigned short hs[TILE * ROWS];
  __shared__ __align__(16) float otile[TILE * 64];

  const int tid  = threadIdx.x;
  const int wv   = tid >> 6;
  const int lane = tid & 63;
  const int c = lane & 15;         // MFMA col / m-row selector
  const int g = lane >> 4;         // MFMA quad group
  const int t2 = lane >> 4;        // which of this wave's 4 nodes
  const int h  = (lane >> 3) & 1;  // neighbor half: k in [16h, 16h+16)
  const int e  = lane & 7;         // 16B feature chunk

  const int node0 = blockIdx.x * TILE;
  const int t = wv * 4 + t2;       // node row within tile
  const int n = node0 + t;

  // ---- per-node row loads issued early (latency overlaps the gather)
  uint4 xrb = {0u,0u,0u,0u};
  f4 xa = {0.f,0.f,0.f,0.f}, xb = {0.f,0.f,0.f,0.f};
  if (h == 0) {
    xrb = *(const uint4*)(xbfB + (size_t)n * 32 + e * 4);
  } else {
    xa = *(const f4*)(x + (size_t)n * 64 + e * 8);
    xb = *(const f4*)(x + (size_t)n * 64 + e * 8 + 4);
  }

  // ---- this lane's 16 neighbor indices: contiguous 64B, 4x int4.
  const int* eib = ei + (size_t)n * 32 + h * 16;
  int4 i0 = *(const int4*)(eib + 0);
  int4 i1 = *(const int4*)(eib + 4);
  int4 i2 = *(const int4*)(eib + 8);
  int4 i3 = *(const int4*)(eib + 12);
  int jj[16] = {i0.x, i0.y, i0.z, i0.w, i1.x, i1.y, i1.z, i1.w,
                i2.x, i2.y, i2.z, i2.w, i3.x, i3.y, i3.z, i3.w};

  // ---- 16 independent gathers (nothing between the loads), then max tree.
  const char* gbase = (const char*)xbfB + (e << 4);
  uint4 r[16];
  #pragma unroll
  for (int i = 0; i < 16; ++i)
    r[i] = *(const uint4*)(gbase + ((size_t)(unsigned)jj[i] << 7));

  uint4 m8[8];
  #pragma unroll
  for (int i = 0; i < 8; ++i) m8[i] = pkmax4(r[2 * i], r[2 * i + 1]);
  uint4 m4[4];
  #pragma unroll
  for (int i = 0; i < 4; ++i) m4[i] = pkmax4(m8[2 * i], m8[2 * i + 1]);
  uint4 m2a = pkmax4(m4[0], m4[1]), m2b = pkmax4(m4[2], m4[3]);
  uint4 macc = pkmax4(m2a, m2b);

  // ---- B fragments: issue while reduce/store/sync run.
  short8 bfrag[4];
  #pragma unroll
  for (int ks = 0; ks < 4; ++ks)
    bfrag[ks] = *(const short8*)(wf + (size_t)((wv * 4 + ks) * 64 + lane) * 8);

  // reduce the h-pair (lane bit 3) in packed domain
  macc.x = pkmax(macc.x, __shfl_xor(macc.x, 8));
  macc.y = pkmax(macc.y, __shfl_xor(macc.y, 8));
  macc.z = pkmax(macc.z, __shfl_xor(macc.z, 8));
  macc.w = pkmax(macc.w, __shfl_xor(macc.w, 8));

  if (h == 0) {
    // diff half: (max_j bf16(x_j+8)) - bf16(x_i+8) -> bias cancels exactly
    uint4 w;
    w.x = pack2(bflo(macc.x) - bflo(xrb.x), bfhi(macc.x) - bfhi(xrb.x));
    w.y = pack2(bflo(macc.y) - bflo(xrb.y), bfhi(macc.y) - bfhi(xrb.y));
    w.z = pack2(bflo(macc.z) - bflo(xrb.z), bfhi(macc.z) - bfhi(xrb.z));
    w.w = pack2(bflo(macc.w) - bflo(xrb.w), bfhi(macc.w) - bfhi(xrb.w));
    *(uint4*)(hs + t * ROWS + 64 + e * 8) = w;
  } else {
    // x half: exact bf16(x) from fp32 source
    uint4 w;
    w.x = pack2(xa.x, xa.y); w.y = pack2(xa.z, xa.w);
    w.z = pack2(xb.x, xb.y); w.w = pack2(xb.z, xb.w);
    *(uint4*)(hs + t * ROWS + e * 8) = w;
  }
  __syncthreads();

  // ---- Phase B: wave wv computes C[:, wv*16 : wv*16+16] via 4 MFMAs.
  f4 acc = {0.f, 0.f, 0.f, 0.f};
  #pragma unroll
  for (int ks = 0; ks < 4; ++ks) {
    // A layout: lane holds A[m=l&15][k=(l>>4)*8+j]
    short8 a = *(const short8*)(hs + c * ROWS + ks * 32 + g * 8);
    acc = __builtin_amdgcn_mfma_f32_16x16x32_bf16(a, bfrag[ks], acc, 0, 0, 0);
  }

  // ---- Epilogue: C layout col=lane&15, row=(lane>>4)*4+reg [m89-verified].
  const float bb = bias[wv * 16 + c];
  #pragma unroll
  for (int j = 0; j < 4; ++j)
    otile[(g * 4 + j) * 64 + wv * 16 + c] = acc[j] + bb;
  __syncthreads();
  *(f4*)(out + (size_t)node0 * 64 + tid * 4) = *(const f4*)&otile[tid * 4];
}

// ---- fallback (ws too small): R2's proven fp32 kernel
#define FWPB 4
#define FROWS 160
__global__ __launch_bounds__(256, 4)
void mrconv_fp32_kernel(const float* __restrict__ x,
                        const int* __restrict__ ei,
                        const float* __restrict__ W,
                        const float* __restrict__ bias,
                        float* __restrict__ out,
                        int n_tiles)
{
  __shared__ __align__(16) unsigned short hsf[FWPB][TILE * FROWS];
  const int wave = threadIdx.x >> 6;
  const int lane = threadIdx.x & 63;
  const int c = lane & 15;
  const int g = lane >> 4;

  short8 bfrag[4][4];
  #pragma unroll
  for (int ks = 0; ks < 4; ++ks) {
    #pragma unroll
    for (int nt = 0; nt < 4; ++nt) {
      short8 v;
      #pragma unroll
      for (int j = 0; j < 8; ++j) {
        int k = ks * 32 + g * 8 + j;
        v[j] = (short)f2bf(W[k * 64 + nt * 16 + c]);
      }
      bfrag[ks][nt] = v;
    }
  }

  const int tile = blockIdx.x * FWPB + wave;
  if (tile >= n_tiles) return;
  const int node0 = tile * TILE;
  unsigned short* hrow = &hsf[wave][0];

  #pragma unroll 2
  for (int t = 0; t < TILE; ++t) {
    const int n = node0 + t;
    const f4 xi = *(const f4*)(x + (size_t)n * 64 + 4 * c);
    f4 m = { -3.4e38f, -3.4e38f, -3.4e38f, -3.4e38f };
    #pragma unroll
    for (int it = 0; it < 8; ++it) {
      const int j = ei[(size_t)n * 32 + it * 4 + g];
      const f4 xj = *(const f4*)(x + (size_t)j * 64 + 4 * c);
      m.x = fmaxf(m.x, xj.x - xi.x);
      m.y = fmaxf(m.y, xj.y - xi.y);
      m.z = fmaxf(m.z, xj.z - xi.z);
      m.w = fmaxf(m.w, xj.w - xi.w);
    }
    m.x = fmaxf(m.x, __shfl_xor(m.x, 16));
    m.y = fmaxf(m.y, __shfl_xor(m.y, 16));
    m.z = fmaxf(m.z, __shfl_xor(m.z, 16));
    m.w = fmaxf(m.w, __shfl_xor(m.w, 16));
    m.x = fmaxf(m.x, __shfl_xor(m.x, 32));
    m.y = fmaxf(m.y, __shfl_xor(m.y, 32));
    m.z = fmaxf(m.z, __shfl_xor(m.z, 32));
    m.w = fmaxf(m.w, __shfl_xor(m.w, 32));
    if (g == 0) {
      ushort4 p;
      p.x = f2bf(xi.x); p.y = f2bf(xi.y); p.z = f2bf(xi.z); p.w = f2bf(xi.w);
      *(ushort4*)(hrow + t * FROWS + 4 * c) = p;
    } else if (g == 1) {
      ushort4 p;
      p.x = f2bf(m.x); p.y = f2bf(m.y); p.z = f2bf(m.z); p.w = f2bf(m.w);
      *(ushort4*)(hrow + t * FROWS + 64 + 4 * c) = p;
    }
  }
  __asm__ volatile("s_waitcnt lgkmcnt(0)" ::: "memory");

  f4 acc[4] = {{0.f,0.f,0.f,0.f},{0.f,0.f,0.f,0.f},{0.f,0.f,0.f,0.f},{0.f,0.f,0.f,0.f}};
  #pragma unroll
  for (int ks = 0; ks < 4; ++ks) {
    short8 a = *(const short8*)(hrow + c * FROWS + ks * 32 + g * 8);
    #pragma unroll
    for (int nt = 0; nt < 4; ++nt)
      acc[nt] = __builtin_amdgcn_mfma_f32_16x16x32_bf16(a, bfrag[ks][nt], acc[nt], 0, 0, 0);
  }
  const int rbase = node0 + g * 4;
  #pragma unroll
  for (int nt = 0; nt < 4; ++nt) {
    const float bb = bias[nt * 16 + c];
    #pragma unroll
    for (int j = 0; j < 4; ++j)
      out[(size_t)(rbase + j) * 64 + nt * 16 + c] = acc[nt][j] + bb;
  }
}

extern "C" void kernel_launch(void* const* d_in, const int* in_sizes, int n_in,
                              void* d_out, int out_size, void* d_ws, size_t ws_size,
                              hipStream_t stream) {
  const float* x  = (const float*)d_in[0];
  const int*   ei = (const int*)d_in[1];     // int64 in reference -> int32 here
  const float* W  = (const float*)d_in[2];
  const float* b  = (const float*)d_in[3];
  float* out = (float*)d_out;

  const int N = in_sizes[0] / 64;            // 100000
  const int n_tiles = N / TILE;              // 6250

  const size_t xbf_bytes = (size_t)N * 64 * 2;   // 12.8 MB
  const size_t wf_bytes  = 1024 * 16;            // 16 KB of B-frags
  if (ws_size >= xbf_bytes + wf_bytes) {
    unsigned int*   xbfB = (unsigned int*)d_ws;
    unsigned short* wf   = (unsigned short*)((char*)d_ws + xbf_bytes);
    const int n8  = N * 64 / 8;                  // 800000
    const int nxb = (n8 + 255) / 256;            // 3125
    hipLaunchKernelGGL(convert_kernel, dim3(nxb + 1), dim3(256), 0, stream,
                       x, xbfB, W, wf, n8, nxb);
    hipLaunchKernelGGL(mrconv5_kernel, dim3(n_tiles), dim3(256), 0, stream,
                       x, xbfB, wf, ei, b, out, n_tiles);
  } else {
    const int blocks = (n_tiles + FWPB - 1) / FWPB;
    hipLaunchKernelGGL(mrconv_fp32_kernel, dim3(blocks), dim3(256), 0, stream,
                       x, ei, W, b, out, n_tiles);
  }
}

// Round 8
// 131.082 us; speedup vs baseline: 1.0376x; 1.0376x over previous
//
#include <hip/hip_runtime.h>
#include <hip/hip_bf16.h>
#include <cstdint>

// DenseMRConv: out = concat([x, max_k(x[idx[n,k]] - x[n])]) @ W + b
// N=100000, K=32, d=64, d_out=64.
//
// R8: force 16 outstanding gathers per lane with one inline-asm block
// (16x global_load_dwordx4 + s_waitcnt vmcnt(0) inside the block) — R5-R7
// proved the compiler pipelines any source-level batch down to ~2 in flight
// (VGPR_Count 32-48). Also: x-half derived from the biased row already in
// registers (bf16((x+8)-8) is exact arithmetic) — fp32 x read eliminated.

typedef __attribute__((ext_vector_type(8))) short short8;
typedef __attribute__((ext_vector_type(4))) float f4;
typedef __attribute__((ext_vector_type(4))) unsigned int u32x4;

#define TILE 16
#define ROWS 168   // padded h row stride in bf16 elems (336 B, 16B-aligned)
#define BIAS 8.0f

__device__ __forceinline__ unsigned short f2bf(float f) {
  unsigned int u = __builtin_bit_cast(unsigned int, f);
  u += 0x7fffu + ((u >> 16) & 1u);          // round-to-nearest-even
  return (unsigned short)(u >> 16);
}
__device__ __forceinline__ unsigned int pack2(float a, float b) {
  return (unsigned int)f2bf(a) | ((unsigned int)f2bf(b) << 16);
}
__device__ __forceinline__ float bflo(unsigned int u) {
  return __builtin_bit_cast(float, u << 16);
}
__device__ __forceinline__ float bfhi(unsigned int u) {
  return __builtin_bit_cast(float, u & 0xffff0000u);
}
__device__ __forceinline__ unsigned int pkmax(unsigned int a, unsigned int b) {
  unsigned int d;
  asm("v_pk_max_u16 %0, %1, %2" : "=v"(d) : "v"(a), "v"(b));
  return d;
}
__device__ __forceinline__ u32x4 pkmax4(u32x4 a, u32x4 b) {
  u32x4 d;
  d.x = pkmax(a.x, b.x); d.y = pkmax(a.y, b.y);
  d.z = pkmax(a.z, b.z); d.w = pkmax(a.w, b.w);
  return d;
}

// ---- pass 1: x -> biased bf16 copy (blocks [0,nxb)), W -> B-frags (block nxb)
__global__ __launch_bounds__(256)
void convert_kernel(const float* __restrict__ x, unsigned int* __restrict__ xbfB,
                    const float* __restrict__ W, unsigned short* __restrict__ wf,
                    int n8, int nxb) {
  if ((int)blockIdx.x < nxb) {
    int i = blockIdx.x * 256 + threadIdx.x;
    if (i >= n8) return;
    const f4* p = (const f4*)x + (size_t)i * 2;
    f4 a = p[0], b = p[1];
    uint4 w;
    w.x = pack2(a.x + BIAS, a.y + BIAS); w.y = pack2(a.z + BIAS, a.w + BIAS);
    w.z = pack2(b.x + BIAS, b.y + BIAS); w.w = pack2(b.z + BIAS, b.w + BIAS);
    ((uint4*)xbfB)[i] = w;
  } else {
    // B layout for mfma_f32_16x16x32_bf16: lane holds B[k=(l>>4)*8+j][n=l&15].
    #pragma unroll
    for (int q = 0; q < 4; ++q) {
      int idx = threadIdx.x * 4 + q;
      int wv = idx >> 8, ks = (idx >> 6) & 3, l = idx & 63;
      int c = l & 15, g = l >> 4;
      short8 v;
      #pragma unroll
      for (int j = 0; j < 8; ++j)
        v[j] = (short)f2bf(W[(ks * 32 + g * 8 + j) * 64 + wv * 16 + c]);
      *(short8*)(wf + (size_t)idx * 8) = v;
    }
  }
}

// ---- pass 2: forced-MLP gather + packed-max + MFMA. One block per 16 nodes.
__global__ __launch_bounds__(256, 4)
void mrconv6_kernel(const unsigned int* __restrict__ xbfB,  // bf16(x+8), 2/uint
                    const unsigned short* __restrict__ wf,  // prebuilt B-frags
                    const int* __restrict__ ei,
                    const float* __restrict__ bias,
                    float* __restrict__ out,
                    int n_tiles)
{
  __shared__ __align__(16) unsigned short hs[TILE * ROWS];
  __shared__ __align__(16) float otile[TILE * 64];

  const int tid  = threadIdx.x;
  const int wv   = tid >> 6;
  const int lane = tid & 63;
  const int c = lane & 15;         // MFMA col / m-row selector
  const int g = lane >> 4;         // MFMA quad group
  const int t2 = lane >> 4;        // which of this wave's 4 nodes
  const int h  = (lane >> 3) & 1;  // neighbor half: k in [16h, 16h+16)
  const int e  = lane & 7;         // 16B feature chunk

  const int node0 = blockIdx.x * TILE;
  const int t = wv * 4 + t2;       // node row within tile
  const int n = node0 + t;

  // ---- own biased row (all lanes): used for diff subtract AND x-half.
  const u32x4 xrb = *(const u32x4*)(xbfB + (size_t)n * 32 + e * 4);

  // ---- this lane's 16 neighbor indices: contiguous 64B, 4x int4.
  const int* eib = ei + (size_t)n * 32 + h * 16;
  int4 i0 = *(const int4*)(eib + 0);
  int4 i1 = *(const int4*)(eib + 4);
  int4 i2 = *(const int4*)(eib + 8);
  int4 i3 = *(const int4*)(eib + 12);

  const int eo = e << 4;
  int o0  = (i0.x << 7) + eo, o1  = (i0.y << 7) + eo;
  int o2  = (i0.z << 7) + eo, o3  = (i0.w << 7) + eo;
  int o4  = (i1.x << 7) + eo, o5  = (i1.y << 7) + eo;
  int o6  = (i1.z << 7) + eo, o7  = (i1.w << 7) + eo;
  int o8  = (i2.x << 7) + eo, o9  = (i2.y << 7) + eo;
  int o10 = (i2.z << 7) + eo, o11 = (i2.w << 7) + eo;
  int o12 = (i3.x << 7) + eo, o13 = (i3.y << 7) + eo;
  int o14 = (i3.z << 7) + eo, o15 = (i3.w << 7) + eo;

  // ---- 16 gathers issued back-to-back, single wait inside the asm block:
  // the HW queues all 16 misses before stalling. Consumers can't be hoisted
  // above the wait because the results flow out of this block.
  u32x4 r0, r1, r2, r3, r4, r5, r6, r7, r8, r9, r10, r11, r12, r13, r14, r15;
  asm volatile(
      "global_load_dwordx4 %[r0],  %[o0],  %[sb]\n\t"
      "global_load_dwordx4 %[r1],  %[o1],  %[sb]\n\t"
      "global_load_dwordx4 %[r2],  %[o2],  %[sb]\n\t"
      "global_load_dwordx4 %[r3],  %[o3],  %[sb]\n\t"
      "global_load_dwordx4 %[r4],  %[o4],  %[sb]\n\t"
      "global_load_dwordx4 %[r5],  %[o5],  %[sb]\n\t"
      "global_load_dwordx4 %[r6],  %[o6],  %[sb]\n\t"
      "global_load_dwordx4 %[r7],  %[o7],  %[sb]\n\t"
      "global_load_dwordx4 %[r8],  %[o8],  %[sb]\n\t"
      "global_load_dwordx4 %[r9],  %[o9],  %[sb]\n\t"
      "global_load_dwordx4 %[r10], %[o10], %[sb]\n\t"
      "global_load_dwordx4 %[r11], %[o11], %[sb]\n\t"
      "global_load_dwordx4 %[r12], %[o12], %[sb]\n\t"
      "global_load_dwordx4 %[r13], %[o13], %[sb]\n\t"
      "global_load_dwordx4 %[r14], %[o14], %[sb]\n\t"
      "global_load_dwordx4 %[r15], %[o15], %[sb]\n\t"
      "s_waitcnt vmcnt(0)"
      : [r0] "=&v"(r0),  [r1] "=&v"(r1),  [r2] "=&v"(r2),  [r3] "=&v"(r3),
        [r4] "=&v"(r4),  [r5] "=&v"(r5),  [r6] "=&v"(r6),  [r7] "=&v"(r7),
        [r8] "=&v"(r8),  [r9] "=&v"(r9),  [r10] "=&v"(r10), [r11] "=&v"(r11),
        [r12] "=&v"(r12), [r13] "=&v"(r13), [r14] "=&v"(r14), [r15] "=&v"(r15)
      : [o0] "v"(o0),  [o1] "v"(o1),  [o2] "v"(o2),  [o3] "v"(o3),
        [o4] "v"(o4),  [o5] "v"(o5),  [o6] "v"(o6),  [o7] "v"(o7),
        [o8] "v"(o8),  [o9] "v"(o9),  [o10] "v"(o10), [o11] "v"(o11),
        [o12] "v"(o12), [o13] "v"(o13), [o14] "v"(o14), [o15] "v"(o15),
        [sb] "s"(xbfB)
      : "memory");

  // ---- packed-u16 max tree (bias makes all values positive -> order-safe)
  u32x4 m0 = pkmax4(pkmax4(r0, r1),  pkmax4(r2, r3));
  u32x4 m1 = pkmax4(pkmax4(r4, r5),  pkmax4(r6, r7));
  u32x4 m2 = pkmax4(pkmax4(r8, r9),  pkmax4(r10, r11));
  u32x4 m3 = pkmax4(pkmax4(r12, r13), pkmax4(r14, r15));
  u32x4 macc = pkmax4(pkmax4(m0, m1), pkmax4(m2, m3));

  // ---- B fragments: issue while reduce/store/sync run.
  short8 bfrag[4];
  #pragma unroll
  for (int ks = 0; ks < 4; ++ks)
    bfrag[ks] = *(const short8*)(wf + (size_t)((wv * 4 + ks) * 64 + lane) * 8);

  // reduce the h-pair (lane bit 3) in packed domain
  macc.x = pkmax(macc.x, __shfl_xor(macc.x, 8));
  macc.y = pkmax(macc.y, __shfl_xor(macc.y, 8));
  macc.z = pkmax(macc.z, __shfl_xor(macc.z, 8));
  macc.w = pkmax(macc.w, __shfl_xor(macc.w, 8));

  if (h == 0) {
    // diff half: (max_j bf16(x_j+8)) - bf16(x_i+8) -> bias cancels exactly
    uint4 w;
    w.x = pack2(bflo(macc.x) - bflo(xrb.x), bfhi(macc.x) - bfhi(xrb.x));
    w.y = pack2(bflo(macc.y) - bflo(xrb.y), bfhi(macc.y) - bfhi(xrb.y));
    w.z = pack2(bflo(macc.z) - bflo(xrb.z), bfhi(macc.z) - bfhi(xrb.z));
    w.w = pack2(bflo(macc.w) - bflo(xrb.w), bfhi(macc.w) - bfhi(xrb.w));
    *(uint4*)(hs + t * ROWS + 64 + e * 8) = w;
  } else {
    // x half: bf16((x+8)_bf16 - 8) — exact arithmetic, no global read
    uint4 w;
    w.x = pack2(bflo(xrb.x) - BIAS, bfhi(xrb.x) - BIAS);
    w.y = pack2(bflo(xrb.y) - BIAS, bfhi(xrb.y) - BIAS);
    w.z = pack2(bflo(xrb.z) - BIAS, bfhi(xrb.z) - BIAS);
    w.w = pack2(bflo(xrb.w) - BIAS, bfhi(xrb.w) - BIAS);
    *(uint4*)(hs + t * ROWS + e * 8) = w;
  }
  __syncthreads();

  // ---- Phase B: wave wv computes C[:, wv*16 : wv*16+16] via 4 MFMAs.
  f4 acc = {0.f, 0.f, 0.f, 0.f};
  #pragma unroll
  for (int ks = 0; ks < 4; ++ks) {
    // A layout: lane holds A[m=l&15][k=(l>>4)*8+j]
    short8 a = *(const short8*)(hs + c * ROWS + ks * 32 + g * 8);
    acc = __builtin_amdgcn_mfma_f32_16x16x32_bf16(a, bfrag[ks], acc, 0, 0, 0);
  }

  // ---- Epilogue: C layout col=lane&15, row=(lane>>4)*4+reg [m89-verified].
  const float bb = bias[wv * 16 + c];
  #pragma unroll
  for (int j = 0; j < 4; ++j)
    otile[(g * 4 + j) * 64 + wv * 16 + c] = acc[j] + bb;
  __syncthreads();
  *(f4*)(out + (size_t)node0 * 64 + tid * 4) = *(const f4*)&otile[tid * 4];
}

// ---- fallback (ws too small): R2's proven fp32 kernel
#define FWPB 4
#define FROWS 160
__global__ __launch_bounds__(256, 4)
void mrconv_fp32_kernel(const float* __restrict__ x,
                        const int* __restrict__ ei,
                        const float* __restrict__ W,
                        const float* __restrict__ bias,
                        float* __restrict__ out,
                        int n_tiles)
{
  __shared__ __align__(16) unsigned short hsf[FWPB][TILE * FROWS];
  const int wave = threadIdx.x >> 6;
  const int lane = threadIdx.x & 63;
  const int c = lane & 15;
  const int g = lane >> 4;

  short8 bfrag[4][4];
  #pragma unroll
  for (int ks = 0; ks < 4; ++ks) {
    #pragma unroll
    for (int nt = 0; nt < 4; ++nt) {
      short8 v;
      #pragma unroll
      for (int j = 0; j < 8; ++j) {
        int k = ks * 32 + g * 8 + j;
        v[j] = (short)f2bf(W[k * 64 + nt * 16 + c]);
      }
      bfrag[ks][nt] = v;
    }
  }

  const int tile = blockIdx.x * FWPB + wave;
  if (tile >= n_tiles) return;
  const int node0 = tile * TILE;
  unsigned short* hrow = &hsf[wave][0];

  #pragma unroll 2
  for (int t = 0; t < TILE; ++t) {
    const int n = node0 + t;
    const f4 xi = *(const f4*)(x + (size_t)n * 64 + 4 * c);
    f4 m = { -3.4e38f, -3.4e38f, -3.4e38f, -3.4e38f };
    #pragma unroll
    for (int it = 0; it < 8; ++it) {
      const int j = ei[(size_t)n * 32 + it * 4 + g];
      const f4 xj = *(const f4*)(x + (size_t)j * 64 + 4 * c);
      m.x = fmaxf(m.x, xj.x - xi.x);
      m.y = fmaxf(m.y, xj.y - xi.y);
      m.z = fmaxf(m.z, xj.z - xi.z);
      m.w = fmaxf(m.w, xj.w - xi.w);
    }
    m.x = fmaxf(m.x, __shfl_xor(m.x, 16));
    m.y = fmaxf(m.y, __shfl_xor(m.y, 16));
    m.z = fmaxf(m.z, __shfl_xor(m.z, 16));
    m.w = fmaxf(m.w, __shfl_xor(m.w, 16));
    m.x = fmaxf(m.x, __shfl_xor(m.x, 32));
    m.y = fmaxf(m.y, __shfl_xor(m.y, 32));
    m.z = fmaxf(m.z, __shfl_xor(m.z, 32));
    m.w = fmaxf(m.w, __shfl_xor(m.w, 32));
    if (g == 0) {
      ushort4 p;
      p.x = f2bf(xi.x); p.y = f2bf(xi.y); p.z = f2bf(xi.z); p.w = f2bf(xi.w);
      *(ushort4*)(hrow + t * FROWS + 4 * c) = p;
    } else if (g == 1) {
      ushort4 p;
      p.x = f2bf(m.x); p.y = f2bf(m.y); p.z = f2bf(m.z); p.w = f2bf(m.w);
      *(ushort4*)(hrow + t * FROWS + 64 + 4 * c) = p;
    }
  }
  __asm__ volatile("s_waitcnt lgkmcnt(0)" ::: "memory");

  f4 acc[4] = {{0.f,0.f,0.f,0.f},{0.f,0.f,0.f,0.f},{0.f,0.f,0.f,0.f},{0.f,0.f,0.f,0.f}};
  #pragma unroll
  for (int ks = 0; ks < 4; ++ks) {
    short8 a = *(const short8*)(hrow + c * FROWS + ks * 32 + g * 8);
    #pragma unroll
    for (int nt = 0; nt < 4; ++nt)
      acc[nt] = __builtin_amdgcn_mfma_f32_16x16x32_bf16(a, bfrag[ks][nt], acc[nt], 0, 0, 0);
  }
  const int rbase = node0 + g * 4;
  #pragma unroll
  for (int nt = 0; nt < 4; ++nt) {
    const float bb = bias[nt * 16 + c];
    #pragma unroll
    for (int j = 0; j < 4; ++j)
      out[(size_t)(rbase + j) * 64 + nt * 16 + c] = acc[nt][j] + bb;
  }
}

extern "C" void kernel_launch(void* const* d_in, const int* in_sizes, int n_in,
                              void* d_out, int out_size, void* d_ws, size_t ws_size,
                              hipStream_t stream) {
  const float* x  = (const float*)d_in[0];
  const int*   ei = (const int*)d_in[1];     // int64 in reference -> int32 here
  const float* W  = (const float*)d_in[2];
  const float* b  = (const float*)d_in[3];
  float* out = (float*)d_out;

  const int N = in_sizes[0] / 64;            // 100000
  const int n_tiles = N / TILE;              // 6250

  const size_t xbf_bytes = (size_t)N * 64 * 2;   // 12.8 MB
  const size_t wf_bytes  = 1024 * 16;            // 16 KB of B-frags
  if (ws_size >= xbf_bytes + wf_bytes) {
    unsigned int*   xbfB = (unsigned int*)d_ws;
    unsigned short* wf   = (unsigned short*)((char*)d_ws + xbf_bytes);
    const int n8  = N * 64 / 8;                  // 800000
    const int nxb = (n8 + 255) / 256;            // 3125
    hipLaunchKernelGGL(convert_kernel, dim3(nxb + 1), dim3(256), 0, stream,
                       x, xbfB, W, wf, n8, nxb);
    hipLaunchKernelGGL(mrconv6_kernel, dim3(n_tiles), dim3(256), 0, stream,
                       xbfB, wf, ei, b, out, n_tiles);
  } else {
    const int blocks = (n_tiles + FWPB - 1) / FWPB;
    hipLaunchKernelGGL(mrconv_fp32_kernel, dim3(blocks), dim3(256), 0, stream,
                       x, ei, W, b, out, n_tiles);
  }
}

// Round 9
// 130.651 us; speedup vs baseline: 1.0410x; 1.0033x over previous
//
#include <hip/hip_runtime.h>
#include <hip/hip_bf16.h>
#include <cstdint>

// DenseMRConv: out = concat([x, max_k(x[idx[n,k]] - x[n])]) @ W + b
// N=100000, K=32, d=64, d_out=64.
//
// R9: the wall is divergent-VMEM address throughput (~1 lane/cyc/CU): the
// 3.2M-row gather = 25.6M divergent lane-slots = 41.7 us floor. Remove the
// REMAINING divergent consumers: ei (was 4x int4 broadcast-divergent) and
// the own-row load are now coalesced half-wave loads + __shfl distribution
// (LDS pipe, not TA). Gather asm block (16 outstanding), packed-u16 max,
// prebuilt W frags, LDS-staged coalesced epilogue all unchanged from R8.

typedef __attribute__((ext_vector_type(8))) short short8;
typedef __attribute__((ext_vector_type(4))) float f4;
typedef __attribute__((ext_vector_type(4))) unsigned int u32x4;

#define TILE 16
#define ROWS 168   // padded h row stride in bf16 elems (336 B, 16B-aligned)
#define BIAS 8.0f

__device__ __forceinline__ unsigned short f2bf(float f) {
  unsigned int u = __builtin_bit_cast(unsigned int, f);
  u += 0x7fffu + ((u >> 16) & 1u);          // round-to-nearest-even
  return (unsigned short)(u >> 16);
}
__device__ __forceinline__ unsigned int pack2(float a, float b) {
  return (unsigned int)f2bf(a) | ((unsigned int)f2bf(b) << 16);
}
__device__ __forceinline__ float bflo(unsigned int u) {
  return __builtin_bit_cast(float, u << 16);
}
__device__ __forceinline__ float bfhi(unsigned int u) {
  return __builtin_bit_cast(float, u & 0xffff0000u);
}
__device__ __forceinline__ unsigned int pkmax(unsigned int a, unsigned int b) {
  unsigned int d;
  asm("v_pk_max_u16 %0, %1, %2" : "=v"(d) : "v"(a), "v"(b));
  return d;
}
__device__ __forceinline__ u32x4 pkmax4(u32x4 a, u32x4 b) {
  u32x4 d;
  d.x = pkmax(a.x, b.x); d.y = pkmax(a.y, b.y);
  d.z = pkmax(a.z, b.z); d.w = pkmax(a.w, b.w);
  return d;
}

// ---- pass 1: x -> biased bf16 copy (blocks [0,nxb)), W -> B-frags (block nxb)
__global__ __launch_bounds__(256)
void convert_kernel(const float* __restrict__ x, unsigned int* __restrict__ xbfB,
                    const float* __restrict__ W, unsigned short* __restrict__ wf,
                    int n8, int nxb) {
  if ((int)blockIdx.x < nxb) {
    int i = blockIdx.x * 256 + threadIdx.x;
    if (i >= n8) return;
    const f4* p = (const f4*)x + (size_t)i * 2;
    f4 a = p[0], b = p[1];
    uint4 w;
    w.x = pack2(a.x + BIAS, a.y + BIAS); w.y = pack2(a.z + BIAS, a.w + BIAS);
    w.z = pack2(b.x + BIAS, b.y + BIAS); w.w = pack2(b.z + BIAS, b.w + BIAS);
    ((uint4*)xbfB)[i] = w;
  } else {
    // B layout for mfma_f32_16x16x32_bf16: lane holds B[k=(l>>4)*8+j][n=l&15].
    #pragma unroll
    for (int q = 0; q < 4; ++q) {
      int idx = threadIdx.x * 4 + q;
      int wv = idx >> 8, ks = (idx >> 6) & 3, l = idx & 63;
      int c = l & 15, g = l >> 4;
      short8 v;
      #pragma unroll
      for (int j = 0; j < 8; ++j)
        v[j] = (short)f2bf(W[(ks * 32 + g * 8 + j) * 64 + wv * 16 + c]);
      *(short8*)(wf + (size_t)idx * 8) = v;
    }
  }
}

// ---- pass 2: forced-MLP gather + packed-max + MFMA. One block per 16 nodes.
__global__ __launch_bounds__(256, 4)
void mrconv7_kernel(const unsigned int* __restrict__ xbfB,  // bf16(x+8), 2/uint
                    const unsigned short* __restrict__ wf,  // prebuilt B-frags
                    const int* __restrict__ ei,
                    const float* __restrict__ bias,
                    float* __restrict__ out,
                    int n_tiles)
{
  __shared__ __align__(16) unsigned short hs[TILE * ROWS];
  __shared__ __align__(16) float otile[TILE * 64];

  const int tid  = threadIdx.x;
  const int wv   = tid >> 6;
  const int lane = tid & 63;
  const int c = lane & 15;         // MFMA col / m-row selector
  const int g = lane >> 4;         // MFMA quad group
  const int t2 = lane >> 4;        // which of this wave's 4 nodes
  const int h  = (lane >> 3) & 1;  // neighbor half: k in [16h, 16h+16)
  const int e  = lane & 7;         // 16B feature chunk

  const int node0 = blockIdx.x * TILE;
  const int t = wv * 4 + t2;       // node row within tile

  // ---- coalesced half-wave loads: wave's 512B of ei + 512B of own rows.
  int4  ei4 = {0, 0, 0, 0};
  uint4 xr4 = {0u, 0u, 0u, 0u};
  if (lane < 32) {
    ei4 = *(const int4*)(ei + ((size_t)(node0 + wv * 4) << 5) + lane * 4);
    xr4 = *(const uint4*)(xbfB + ((size_t)(node0 + wv * 4) << 5) + lane * 4);
  }

  // ---- distribute via shuffles (LDS pipe, zero TA cost).
  // lane needs ei int4-blocks [t2*8+h*4 .. +4) and own-row uint4 block t2*8+e.
  const int se = t2 * 8 + h * 4;
  int4 b0, b1, b2, b3;
  b0.x = __shfl(ei4.x, se);     b0.y = __shfl(ei4.y, se);
  b0.z = __shfl(ei4.z, se);     b0.w = __shfl(ei4.w, se);
  b1.x = __shfl(ei4.x, se + 1); b1.y = __shfl(ei4.y, se + 1);
  b1.z = __shfl(ei4.z, se + 1); b1.w = __shfl(ei4.w, se + 1);
  b2.x = __shfl(ei4.x, se + 2); b2.y = __shfl(ei4.y, se + 2);
  b2.z = __shfl(ei4.z, se + 2); b2.w = __shfl(ei4.w, se + 2);
  b3.x = __shfl(ei4.x, se + 3); b3.y = __shfl(ei4.y, se + 3);
  b3.z = __shfl(ei4.z, se + 3); b3.w = __shfl(ei4.w, se + 3);

  const int sx = t2 * 8 + e;
  u32x4 xrb;
  xrb.x = (unsigned)__shfl((int)xr4.x, sx);
  xrb.y = (unsigned)__shfl((int)xr4.y, sx);
  xrb.z = (unsigned)__shfl((int)xr4.z, sx);
  xrb.w = (unsigned)__shfl((int)xr4.w, sx);

  const int eo = e << 4;
  int o0  = (b0.x << 7) + eo, o1  = (b0.y << 7) + eo;
  int o2  = (b0.z << 7) + eo, o3  = (b0.w << 7) + eo;
  int o4  = (b1.x << 7) + eo, o5  = (b1.y << 7) + eo;
  int o6  = (b1.z << 7) + eo, o7  = (b1.w << 7) + eo;
  int o8  = (b2.x << 7) + eo, o9  = (b2.y << 7) + eo;
  int o10 = (b2.z << 7) + eo, o11 = (b2.w << 7) + eo;
  int o12 = (b3.x << 7) + eo, o13 = (b3.y << 7) + eo;
  int o14 = (b3.z << 7) + eo, o15 = (b3.w << 7) + eo;

  // ---- 16 gathers issued back-to-back, single wait inside the asm block.
  u32x4 r0, r1, r2, r3, r4, r5, r6, r7, r8, r9, r10, r11, r12, r13, r14, r15;
  asm volatile(
      "global_load_dwordx4 %[r0],  %[o0],  %[sb]\n\t"
      "global_load_dwordx4 %[r1],  %[o1],  %[sb]\n\t"
      "global_load_dwordx4 %[r2],  %[o2],  %[sb]\n\t"
      "global_load_dwordx4 %[r3],  %[o3],  %[sb]\n\t"
      "global_load_dwordx4 %[r4],  %[o4],  %[sb]\n\t"
      "global_load_dwordx4 %[r5],  %[o5],  %[sb]\n\t"
      "global_load_dwordx4 %[r6],  %[o6],  %[sb]\n\t"
      "global_load_dwordx4 %[r7],  %[o7],  %[sb]\n\t"
      "global_load_dwordx4 %[r8],  %[o8],  %[sb]\n\t"
      "global_load_dwordx4 %[r9],  %[o9],  %[sb]\n\t"
      "global_load_dwordx4 %[r10], %[o10], %[sb]\n\t"
      "global_load_dwordx4 %[r11], %[o11], %[sb]\n\t"
      "global_load_dwordx4 %[r12], %[o12], %[sb]\n\t"
      "global_load_dwordx4 %[r13], %[o13], %[sb]\n\t"
      "global_load_dwordx4 %[r14], %[o14], %[sb]\n\t"
      "global_load_dwordx4 %[r15], %[o15], %[sb]\n\t"
      "s_waitcnt vmcnt(0)"
      : [r0] "=&v"(r0),  [r1] "=&v"(r1),  [r2] "=&v"(r2),  [r3] "=&v"(r3),
        [r4] "=&v"(r4),  [r5] "=&v"(r5),  [r6] "=&v"(r6),  [r7] "=&v"(r7),
        [r8] "=&v"(r8),  [r9] "=&v"(r9),  [r10] "=&v"(r10), [r11] "=&v"(r11),
        [r12] "=&v"(r12), [r13] "=&v"(r13), [r14] "=&v"(r14), [r15] "=&v"(r15)
      : [o0] "v"(o0),  [o1] "v"(o1),  [o2] "v"(o2),  [o3] "v"(o3),
        [o4] "v"(o4),  [o5] "v"(o5),  [o6] "v"(o6),  [o7] "v"(o7),
        [o8] "v"(o8),  [o9] "v"(o9),  [o10] "v"(o10), [o11] "v"(o11),
        [o12] "v"(o12), [o13] "v"(o13), [o14] "v"(o14), [o15] "v"(o15),
        [sb] "s"(xbfB)
      : "memory");

  // ---- packed-u16 max tree (bias makes all values positive -> order-safe)
  u32x4 m0 = pkmax4(pkmax4(r0, r1),  pkmax4(r2, r3));
  u32x4 m1 = pkmax4(pkmax4(r4, r5),  pkmax4(r6, r7));
  u32x4 m2 = pkmax4(pkmax4(r8, r9),  pkmax4(r10, r11));
  u32x4 m3 = pkmax4(pkmax4(r12, r13), pkmax4(r14, r15));
  u32x4 macc = pkmax4(pkmax4(m0, m1), pkmax4(m2, m3));

  // ---- B fragments: coalesced, issued while reduce/store/sync run.
  short8 bfrag[4];
  #pragma unroll
  for (int ks = 0; ks < 4; ++ks)
    bfrag[ks] = *(const short8*)(wf + (size_t)((wv * 4 + ks) * 64 + lane) * 8);

  // reduce the h-pair (lane bit 3) in packed domain
  macc.x = pkmax(macc.x, __shfl_xor(macc.x, 8));
  macc.y = pkmax(macc.y, __shfl_xor(macc.y, 8));
  macc.z = pkmax(macc.z, __shfl_xor(macc.z, 8));
  macc.w = pkmax(macc.w, __shfl_xor(macc.w, 8));

  if (h == 0) {
    // diff half: (max_j bf16(x_j+8)) - bf16(x_i+8) -> bias cancels exactly
    uint4 w;
    w.x = pack2(bflo(macc.x) - bflo(xrb.x), bfhi(macc.x) - bfhi(xrb.x));
    w.y = pack2(bflo(macc.y) - bflo(xrb.y), bfhi(macc.y) - bfhi(xrb.y));
    w.z = pack2(bflo(macc.z) - bflo(xrb.z), bfhi(macc.z) - bfhi(xrb.z));
    w.w = pack2(bflo(macc.w) - bflo(xrb.w), bfhi(macc.w) - bfhi(xrb.w));
    *(uint4*)(hs + t * ROWS + 64 + e * 8) = w;
  } else {
    // x half: bf16((x+8)_bf16 - 8) — exact arithmetic, no global read
    uint4 w;
    w.x = pack2(bflo(xrb.x) - BIAS, bfhi(xrb.x) - BIAS);
    w.y = pack2(bflo(xrb.y) - BIAS, bfhi(xrb.y) - BIAS);
    w.z = pack2(bflo(xrb.z) - BIAS, bfhi(xrb.z) - BIAS);
    w.w = pack2(bflo(xrb.w) - BIAS, bfhi(xrb.w) - BIAS);
    *(uint4*)(hs + t * ROWS + e * 8) = w;
  }
  __syncthreads();

  // ---- Phase B: wave wv computes C[:, wv*16 : wv*16+16] via 4 MFMAs.
  f4 acc = {0.f, 0.f, 0.f, 0.f};
  #pragma unroll
  for (int ks = 0; ks < 4; ++ks) {
    // A layout: lane holds A[m=l&15][k=(l>>4)*8+j]
    short8 a = *(const short8*)(hs + c * ROWS + ks * 32 + g * 8);
    acc = __builtin_amdgcn_mfma_f32_16x16x32_bf16(a, bfrag[ks], acc, 0, 0, 0);
  }

  // ---- Epilogue: C layout col=lane&15, row=(lane>>4)*4+reg [m89-verified].
  const float bb = bias[wv * 16 + c];
  #pragma unroll
  for (int j = 0; j < 4; ++j)
    otile[(g * 4 + j) * 64 + wv * 16 + c] = acc[j] + bb;
  __syncthreads();
  *(f4*)(out + (size_t)node0 * 64 + tid * 4) = *(const f4*)&otile[tid * 4];
}

// ---- fallback (ws too small): R2's proven fp32 kernel
#define FWPB 4
#define FROWS 160
__global__ __launch_bounds__(256, 4)
void mrconv_fp32_kernel(const float* __restrict__ x,
                        const int* __restrict__ ei,
                        const float* __restrict__ W,
                        const float* __restrict__ bias,
                        float* __restrict__ out,
                        int n_tiles)
{
  __shared__ __align__(16) unsigned short hsf[FWPB][TILE * FROWS];
  const int wave = threadIdx.x >> 6;
  const int lane = threadIdx.x & 63;
  const int c = lane & 15;
  const int g = lane >> 4;

  short8 bfrag[4][4];
  #pragma unroll
  for (int ks = 0; ks < 4; ++ks) {
    #pragma unroll
    for (int nt = 0; nt < 4; ++nt) {
      short8 v;
      #pragma unroll
      for (int j = 0; j < 8; ++j) {
        int k = ks * 32 + g * 8 + j;
        v[j] = (short)f2bf(W[k * 64 + nt * 16 + c]);
      }
      bfrag[ks][nt] = v;
    }
  }

  const int tile = blockIdx.x * FWPB + wave;
  if (tile >= n_tiles) return;
  const int node0 = tile * TILE;
  unsigned short* hrow = &hsf[wave][0];

  #pragma unroll 2
  for (int t = 0; t < TILE; ++t) {
    const int n = node0 + t;
    const f4 xi = *(const f4*)(x + (size_t)n * 64 + 4 * c);
    f4 m = { -3.4e38f, -3.4e38f, -3.4e38f, -3.4e38f };
    #pragma unroll
    for (int it = 0; it < 8; ++it) {
      const int j = ei[(size_t)n * 32 + it * 4 + g];
      const f4 xj = *(const f4*)(x + (size_t)j * 64 + 4 * c);
      m.x = fmaxf(m.x, xj.x - xi.x);
      m.y = fmaxf(m.y, xj.y - xi.y);
      m.z = fmaxf(m.z, xj.z - xi.z);
      m.w = fmaxf(m.w, xj.w - xi.w);
    }
    m.x = fmaxf(m.x, __shfl_xor(m.x, 16));
    m.y = fmaxf(m.y, __shfl_xor(m.y, 16));
    m.z = fmaxf(m.z, __shfl_xor(m.z, 16));
    m.w = fmaxf(m.w, __shfl_xor(m.w, 16));
    m.x = fmaxf(m.x, __shfl_xor(m.x, 32));
    m.y = fmaxf(m.y, __shfl_xor(m.y, 32));
    m.z = fmaxf(m.z, __shfl_xor(m.z, 32));
    m.w = fmaxf(m.w, __shfl_xor(m.w, 32));
    if (g == 0) {
      ushort4 p;
      p.x = f2bf(xi.x); p.y = f2bf(xi.y); p.z = f2bf(xi.z); p.w = f2bf(xi.w);
      *(ushort4*)(hrow + t * FROWS + 4 * c) = p;
    } else if (g == 1) {
      ushort4 p;
      p.x = f2bf(m.x); p.y = f2bf(m.y); p.z = f2bf(m.z); p.w = f2bf(m.w);
      *(ushort4*)(hrow + t * FROWS + 64 + 4 * c) = p;
    }
  }
  __asm__ volatile("s_waitcnt lgkmcnt(0)" ::: "memory");

  f4 acc[4] = {{0.f,0.f,0.f,0.f},{0.f,0.f,0.f,0.f},{0.f,0.f,0.f,0.f},{0.f,0.f,0.f,0.f}};
  #pragma unroll
  for (int ks = 0; ks < 4; ++ks) {
    short8 a = *(const short8*)(hrow + c * FROWS + ks * 32 + g * 8);
    #pragma unroll
    for (int nt = 0; nt < 4; ++nt)
      acc[nt] = __builtin_amdgcn_mfma_f32_16x16x32_bf16(a, bfrag[ks][nt], acc[nt], 0, 0, 0);
  }
  const int rbase = node0 + g * 4;
  #pragma unroll
  for (int nt = 0; nt < 4; ++nt) {
    const float bb = bias[nt * 16 + c];
    #pragma unroll
    for (int j = 0; j < 4; ++j)
      out[(size_t)(rbase + j) * 64 + nt * 16 + c] = acc[nt][j] + bb;
  }
}

extern "C" void kernel_launch(void* const* d_in, const int* in_sizes, int n_in,
                              void* d_out, int out_size, void* d_ws, size_t ws_size,
                              hipStream_t stream) {
  const float* x  = (const float*)d_in[0];
  const int*   ei = (const int*)d_in[1];     // int64 in reference -> int32 here
  const float* W  = (const float*)d_in[2];
  const float* b  = (const float*)d_in[3];
  float* out = (float*)d_out;

  const int N = in_sizes[0] / 64;            // 100000
  const int n_tiles = N / TILE;              // 6250

  const size_t xbf_bytes = (size_t)N * 64 * 2;   // 12.8 MB
  const size_t wf_bytes  = 1024 * 16;            // 16 KB of B-frags
  if (ws_size >= xbf_bytes + wf_bytes) {
    unsigned int*   xbfB = (unsigned int*)d_ws;
    unsigned short* wf   = (unsigned short*)((char*)d_ws + xbf_bytes);
    const int n8  = N * 64 / 8;                  // 800000
    const int nxb = (n8 + 255) / 256;            // 3125
    hipLaunchKernelGGL(convert_kernel, dim3(nxb + 1), dim3(256), 0, stream,
                       x, xbfB, W, wf, n8, nxb);
    hipLaunchKernelGGL(mrconv7_kernel, dim3(n_tiles), dim3(256), 0, stream,
                       xbfB, wf, ei, b, out, n_tiles);
  } else {
    const int blocks = (n_tiles + FWPB - 1) / FWPB;
    hipLaunchKernelGGL(mrconv_fp32_kernel, dim3(blocks), dim3(256), 0, stream,
                       x, ei, W, b, out, n_tiles);
  }
}